// Round 9
// baseline (189.795 us; speedup 1.0000x reference)
//
#include <hip/hip_runtime.h>
#include <math.h>

#define N_NODES 50000
#define N_EDGES 800000
#define HEADS 4
#define OUT_C 64
#define HC 256            // HEADS*OUT_C
#define NEG_SLOPE 0.2f
#define N_CHUNKS ((N_NODES + 255) / 256)   // 196
#define GEMM_ROWS 16
#define GEMM_BLOCKS (N_NODES / GEMM_ROWS)  // 3125
#define HIST_BLOCKS (N_EDGES / 256)        // 3125

// float -> bf16 (round-to-nearest-even); inputs are finite
__device__ inline unsigned short f2bf(float f) {
    unsigned u = __float_as_uint(f);
    return (unsigned short)((u + 0x7FFFu + ((u >> 16) & 1u)) >> 16);
}
__device__ inline float bf2f(unsigned short h) {
    return __uint_as_float(((unsigned)h) << 16);
}

// sum across the 16 lanes of a DPP row (head group) via row_ror adds: pure VALU
__device__ inline float rowsum16(float p) {
    int y;
    y = __builtin_amdgcn_update_dpp(0, __float_as_int(p), 0x121, 0xF, 0xF, false);
    p += __int_as_float(y);
    y = __builtin_amdgcn_update_dpp(0, __float_as_int(p), 0x122, 0xF, 0xF, false);
    p += __int_as_float(y);
    y = __builtin_amdgcn_update_dpp(0, __float_as_int(p), 0x124, 0xF, 0xF, false);
    p += __int_as_float(y);
    y = __builtin_amdgcn_update_dpp(0, __float_as_int(p), 0x128, 0xF, 0xF, false);
    p += __int_as_float(y);
    return p;
}

// ---- fused: blocks [0,3125) do xl=bf16(x@W); blocks [3125,6250) histogram dst ----
__global__ void k_gemm_hist(const float* __restrict__ x, const float* __restrict__ W,
                            unsigned short* __restrict__ xlh,
                            const int* __restrict__ dst, int* __restrict__ cnt) {
    __shared__ float xr[GEMM_ROWS][OUT_C];
    int b = blockIdx.x;
    int t = threadIdx.x;
    if (b >= GEMM_BLOCKS) {
        int e = (b - GEMM_BLOCKS) * 256 + t;       // exactly covers N_EDGES
        atomicAdd(&cnt[dst[e]], 1);
        return;
    }
    int row0 = b * GEMM_ROWS;
    #pragma unroll
    for (int i = t; i < GEMM_ROWS * OUT_C; i += 256) {
        int r = i / OUT_C, c = i % OUT_C;
        xr[r][c] = x[(row0 + r) * OUT_C + c];
    }
    __syncthreads();
    float acc[GEMM_ROWS];
    #pragma unroll
    for (int r = 0; r < GEMM_ROWS; ++r) acc[r] = 0.0f;
    #pragma unroll
    for (int k = 0; k < OUT_C; ++k) {
        float w = W[k * HC + t];
        #pragma unroll
        for (int r = 0; r < GEMM_ROWS; ++r) acc[r] += xr[r][k] * w;
    }
    #pragma unroll
    for (int r = 0; r < GEMM_ROWS; ++r) xlh[(size_t)(row0 + r) * HC + t] = f2bf(acc[r]);
}

// ---- fused scan: per-chunk local exclusive scan + last-block scans chunk totals ----
__global__ void k_scan(const int* __restrict__ cnt, int* __restrict__ rowL,
                       int* __restrict__ tops, int* __restrict__ topsS,
                       int* __restrict__ done) {
    __shared__ int wsum[4];
    __shared__ int wsum2[4];
    __shared__ int lastflag;
    int t = threadIdx.x, b = blockIdx.x;
    int idx = b * 256 + t;
    int v = (idx < N_NODES) ? cnt[idx] : 0;
    int lane = t & 63, w = t >> 6;
    int x = v;
    #pragma unroll
    for (int off = 1; off < 64; off <<= 1) {
        int y = __shfl_up(x, off);
        if (lane >= off) x += y;
    }
    if (lane == 63) wsum[w] = x;
    __syncthreads();
    if (t == 0) {
        int s0 = wsum[0], s1 = wsum[1], s2 = wsum[2], s3 = wsum[3];
        wsum[0] = 0; wsum[1] = s0; wsum[2] = s0 + s1; wsum[3] = s0 + s1 + s2;
        tops[b] = s0 + s1 + s2 + s3;
    }
    __syncthreads();
    if (idx < N_NODES) rowL[idx] = x - v + wsum[w];
    // last block to arrive scans the chunk totals
    __threadfence();
    if (t == 0) lastflag = (atomicAdd(done, 1) == N_CHUNKS - 1);
    __syncthreads();
    if (!lastflag) return;
    __threadfence();
    int v2 = (t < N_CHUNKS) ? tops[t] : 0;
    int x2 = v2;
    #pragma unroll
    for (int off = 1; off < 64; off <<= 1) {
        int y = __shfl_up(x2, off);
        if (lane >= off) x2 += y;
    }
    if (lane == 63) wsum2[w] = x2;
    __syncthreads();
    if (t == 0) {
        int s0 = wsum2[0], s1 = wsum2[1], s2 = wsum2[2];
        wsum2[0] = 0; wsum2[1] = s0; wsum2[2] = s0 + s1; wsum2[3] = s0 + s1 + s2;
    }
    __syncthreads();
    topsS[t] = x2 - v2 + wsum2[w];
}

// scatter src ids into dst-sorted order; cnt counts back down (acts as cursor);
// tail threads write 16 sentinel zeros so k_node's prefetch can run unclamped
__global__ void k_fill(const int* __restrict__ src, const int* __restrict__ dst,
                       int* __restrict__ cnt, const int* __restrict__ rowL,
                       const int* __restrict__ topsS, int* __restrict__ ssorted) {
    int e = blockIdx.x * blockDim.x + threadIdx.x;
    if (e >= N_EDGES) {
        if (e < N_EDGES + 16) ssorted[e] = 0;
        return;
    }
    int d = dst[e];
    int slot = atomicAdd(&cnt[d], -1) - 1;          // unique in [0, deg)
    int pos = rowL[d] + topsS[d >> 8] + slot;
    ssorted[pos] = src[e];
}

// ---------------- fused softmax + aggregate: one WAVE per node ----------------
// lane owns channels [4*lane, 4*lane+4); head = lane>>4 (16 lanes per head).
// bf16 rows (512 B); no max-subtraction (shift-invariant, |score| O(10)).
__global__ __launch_bounds__(256) void k_node(
    const unsigned short* __restrict__ xlh, const int* __restrict__ rowL,
    const int* __restrict__ topsS, const int* __restrict__ ssorted,
    const float* __restrict__ att, const float* __restrict__ bias,
    float* __restrict__ out) {
    int w = threadIdx.x >> 6;
    int lane = threadIdx.x & 63;
    int n = blockIdx.x * 4 + w;                    // grid = 12500 exact
    int start = rowL[n] + topsS[n >> 8];
    int end = (n == N_NODES - 1) ? N_EDGES : (rowL[n + 1] + topsS[(n + 1) >> 8]);
    start = __builtin_amdgcn_readfirstlane(start); // scalar edge-list walk
    end   = __builtin_amdgcn_readfirstlane(end);
    int ne = end - start;
    const int* sp = ssorted + start;
    int c4 = lane << 2;
    const unsigned short* xp = xlh + c4;
    ushort4 xq = *(const ushort4*)(xp + (size_t)n * HC);
    float4 xn = make_float4(bf2f(xq.x), bf2f(xq.y), bf2f(xq.z), bf2f(xq.w));
    const float4 at = *(const float4*)(att + c4);
    float4 acc = make_float4(0.f, 0.f, 0.f, 0.f);
    float den = 0.0f;

#define EDGE(vq) {                                                        \
        float4 vc = make_float4(bf2f(vq.x), bf2f(vq.y),                   \
                                bf2f(vq.z), bf2f(vq.w));                  \
        float f, p;                                                       \
        f = xn.x + vc.x; f = f > 0.f ? f : NEG_SLOPE * f; p  = f * at.x;  \
        f = xn.y + vc.y; f = f > 0.f ? f : NEG_SLOPE * f; p += f * at.y;  \
        f = xn.z + vc.z; f = f > 0.f ? f : NEG_SLOPE * f; p += f * at.z;  \
        f = xn.w + vc.w; f = f > 0.f ? f : NEG_SLOPE * f; p += f * at.w;  \
        p = rowsum16(p);                                                  \
        float ex = __expf(p);                                             \
        den += ex;                                                        \
        acc.x += ex * vc.x; acc.y += ex * vc.y;                           \
        acc.z += ex * vc.z; acc.w += ex * vc.w; }

    if (ne > 0) {
        // depth-2 pipeline; prefetch indices/rows run into the 16-int sentinel pad
        int sa = sp[0];
        int sb = sp[1];
        ushort4 va = *(const ushort4*)(xp + (size_t)sa * HC);
        ushort4 vb = *(const ushort4*)(xp + (size_t)sb * HC);
        sa = sp[2];
        sb = sp[3];
        int i = 0;
        for (; i + 1 < ne; i += 2) {
            ushort4 v0 = va, v1 = vb;
            va = *(const ushort4*)(xp + (size_t)sa * HC);
            vb = *(const ushort4*)(xp + (size_t)sb * HC);
            sa = sp[i + 4];
            sb = sp[i + 5];
            EDGE(v0);
            EDGE(v1);
        }
        if (i < ne) EDGE(va);
    }
#undef EDGE

    float r = 1.0f / (den > 0.0f ? den : 1.0f);
    const float4 b4 = *(const float4*)(bias + c4);
    float4 o;
    o.x = fmaxf(acc.x * r + b4.x, 0.0f);
    o.y = fmaxf(acc.y * r + b4.y, 0.0f);
    o.z = fmaxf(acc.z * r + b4.z, 0.0f);
    o.w = fmaxf(acc.w * r + b4.w, 0.0f);
    *(float4*)(out + (size_t)n * HC + c4) = o;
}

extern "C" void kernel_launch(void* const* d_in, const int* in_sizes, int n_in,
                              void* d_out, int out_size, void* d_ws, size_t ws_size,
                              hipStream_t stream) {
    const float* x    = (const float*)d_in[0];
    const int*   edge = (const int*)d_in[1];     // [2, E] int32
    const float* W    = (const float*)d_in[2];
    const float* att  = (const float*)d_in[3];
    const float* bias = (const float*)d_in[4];
    float* out = (float*)d_out;

    const int* src = edge;
    const int* dst = edge + N_EDGES;

    // workspace layout (16B-aligned)
    char* ws = (char*)d_ws;
    unsigned short* xlh = (unsigned short*)ws;          // 25,600,000 B (bf16 xl)
    int* cnt     = (int*)(ws + 25600000);               //   200,000 B
    int* done    = (int*)(ws + 25800000);               //        64 B (memset w/ cnt)
    int* rowL    = (int*)(ws + 25800064);               //   200,000 B
    int* ssorted = (int*)(ws + 26000064);               // 3,200,064 B (+16 pad ints)
    int* tops    = (int*)(ws + 29200192);               //     1,024 B
    int* topsS   = (int*)(ws + 29201216);               //     1,024 B
    // total ~29.2 MB

    hipMemsetAsync(cnt, 0, 200064, stream);  // cnt + done
    k_gemm_hist<<<GEMM_BLOCKS + HIST_BLOCKS, 256, 0, stream>>>(x, W, xlh, dst, cnt);
    k_scan<<<N_CHUNKS, 256, 0, stream>>>(cnt, rowL, tops, topsS, done);
    k_fill<<<(N_EDGES + 16 + 255) / 256, 256, 0, stream>>>(src, dst, cnt, rowL, topsS, ssorted);
    k_node<<<N_NODES / 4, 256, 0, stream>>>(xlh, rowL, topsS, ssorted, att, bias, out);
}

// Round 10
// 186.690 us; speedup vs baseline: 1.0166x; 1.0166x over previous
//
#include <hip/hip_runtime.h>
#include <math.h>

#define N_NODES 50000
#define N_EDGES 800000
#define HEADS 4
#define OUT_C 64
#define HC 256            // HEADS*OUT_C
#define NEG_SLOPE 0.2f
#define N_CHUNKS ((N_NODES + 255) / 256)   // 196
#define GEMM_ROWS 16
#define GEMM_BLOCKS (N_NODES / GEMM_ROWS)  // 3125
#define HIST_BLOCKS (N_EDGES / 256)        // 3125

// float -> bf16 (round-to-nearest-even); inputs are finite
__device__ inline unsigned short f2bf(float f) {
    unsigned u = __float_as_uint(f);
    return (unsigned short)((u + 0x7FFFu + ((u >> 16) & 1u)) >> 16);
}
__device__ inline float bf2f(unsigned short h) {
    return __uint_as_float(((unsigned)h) << 16);
}

// sum across the 16 lanes of a DPP row (head group) via row_ror adds: pure VALU
__device__ inline float rowsum16(float p) {
    int y;
    y = __builtin_amdgcn_update_dpp(0, __float_as_int(p), 0x121, 0xF, 0xF, false);
    p += __int_as_float(y);
    y = __builtin_amdgcn_update_dpp(0, __float_as_int(p), 0x122, 0xF, 0xF, false);
    p += __int_as_float(y);
    y = __builtin_amdgcn_update_dpp(0, __float_as_int(p), 0x124, 0xF, 0xF, false);
    p += __int_as_float(y);
    y = __builtin_amdgcn_update_dpp(0, __float_as_int(p), 0x128, 0xF, 0xF, false);
    p += __int_as_float(y);
    return p;
}

// ---- fused: blocks [0,3125) do xl=bf16(x@W); blocks [3125,6250) histogram dst ----
// GEMM reads x via wave-uniform addresses -> compiler emits s_load (SMEM pipe),
// FMAs become v_fmac(vgpr, sgpr, vgpr). No LDS, no syncthreads.
__global__ void k_gemm_hist(const float* __restrict__ x, const float* __restrict__ W,
                            unsigned short* __restrict__ xlh,
                            const int* __restrict__ dst, int* __restrict__ cnt) {
    int b = blockIdx.x;
    int t = threadIdx.x;
    if (b >= GEMM_BLOCKS) {
        int e = (b - GEMM_BLOCKS) * 256 + t;       // exactly covers N_EDGES
        atomicAdd(&cnt[dst[e]], 1);
        return;
    }
    int row0 = b * GEMM_ROWS;
    const float* xb = x + (size_t)row0 * OUT_C;
    float acc[GEMM_ROWS];
    #pragma unroll
    for (int r = 0; r < GEMM_ROWS; ++r) acc[r] = 0.0f;
    #pragma unroll 4
    for (int k = 0; k < OUT_C; ++k) {
        float w = W[(size_t)k * HC + t];
        #pragma unroll
        for (int r = 0; r < GEMM_ROWS; ++r)
            acc[r] += xb[r * OUT_C + k] * w;       // uniform addr -> s_load
    }
    #pragma unroll
    for (int r = 0; r < GEMM_ROWS; ++r)
        xlh[(size_t)(row0 + r) * HC + t] = f2bf(acc[r]);
}

// ---- fused scan: per-chunk local exclusive scan + last-block scans chunk totals ----
__global__ void k_scan(const int* __restrict__ cnt, int* __restrict__ rowL,
                       int* __restrict__ tops, int* __restrict__ topsS,
                       int* __restrict__ done) {
    __shared__ int wsum[4];
    __shared__ int wsum2[4];
    __shared__ int lastflag;
    int t = threadIdx.x, b = blockIdx.x;
    int idx = b * 256 + t;
    int v = (idx < N_NODES) ? cnt[idx] : 0;
    int lane = t & 63, w = t >> 6;
    int x = v;
    #pragma unroll
    for (int off = 1; off < 64; off <<= 1) {
        int y = __shfl_up(x, off);
        if (lane >= off) x += y;
    }
    if (lane == 63) wsum[w] = x;
    __syncthreads();
    if (t == 0) {
        int s0 = wsum[0], s1 = wsum[1], s2 = wsum[2], s3 = wsum[3];
        wsum[0] = 0; wsum[1] = s0; wsum[2] = s0 + s1; wsum[3] = s0 + s1 + s2;
        tops[b] = s0 + s1 + s2 + s3;
    }
    __syncthreads();
    if (idx < N_NODES) rowL[idx] = x - v + wsum[w];
    // last block to arrive scans the chunk totals
    __threadfence();
    if (t == 0) lastflag = (atomicAdd(done, 1) == N_CHUNKS - 1);
    __syncthreads();
    if (!lastflag) return;
    __threadfence();
    int v2 = (t < N_CHUNKS) ? tops[t] : 0;
    int x2 = v2;
    #pragma unroll
    for (int off = 1; off < 64; off <<= 1) {
        int y = __shfl_up(x2, off);
        if (lane >= off) x2 += y;
    }
    if (lane == 63) wsum2[w] = x2;
    __syncthreads();
    if (t == 0) {
        int s0 = wsum2[0], s1 = wsum2[1], s2 = wsum2[2];
        wsum2[0] = 0; wsum2[1] = s0; wsum2[2] = s0 + s1; wsum2[3] = s0 + s1 + s2;
    }
    __syncthreads();
    topsS[t] = x2 - v2 + wsum2[w];
}

// scatter src ids into dst-sorted order; cnt counts back down (acts as cursor);
// tail threads write 16 sentinel zeros so k_node's prefetch can run unclamped
__global__ void k_fill(const int* __restrict__ src, const int* __restrict__ dst,
                       int* __restrict__ cnt, const int* __restrict__ rowL,
                       const int* __restrict__ topsS, int* __restrict__ ssorted) {
    int e = blockIdx.x * blockDim.x + threadIdx.x;
    if (e >= N_EDGES) {
        if (e < N_EDGES + 16) ssorted[e] = 0;
        return;
    }
    int d = dst[e];
    int slot = atomicAdd(&cnt[d], -1) - 1;          // unique in [0, deg)
    int pos = rowL[d] + topsS[d >> 8] + slot;
    ssorted[pos] = src[e];
}

// ---------------- fused softmax + aggregate: one WAVE per node ----------------
// lane owns channels [4*lane, 4*lane+4); head = lane>>4 (16 lanes per head).
// bf16 rows (512 B); no max-subtraction (shift-invariant, |score| O(10)).
__global__ __launch_bounds__(256) void k_node(
    const unsigned short* __restrict__ xlh, const int* __restrict__ rowL,
    const int* __restrict__ topsS, const int* __restrict__ ssorted,
    const float* __restrict__ att, const float* __restrict__ bias,
    float* __restrict__ out) {
    int w = threadIdx.x >> 6;
    int lane = threadIdx.x & 63;
    int n = blockIdx.x * 4 + w;                    // grid = 12500 exact
    int start = rowL[n] + topsS[n >> 8];
    int end = (n == N_NODES - 1) ? N_EDGES : (rowL[n + 1] + topsS[(n + 1) >> 8]);
    start = __builtin_amdgcn_readfirstlane(start); // scalar edge-list walk
    end   = __builtin_amdgcn_readfirstlane(end);
    int ne = end - start;
    const int* sp = ssorted + start;
    int c4 = lane << 2;
    const unsigned short* xp = xlh + c4;
    ushort4 xq = *(const ushort4*)(xp + (size_t)n * HC);
    float4 xn = make_float4(bf2f(xq.x), bf2f(xq.y), bf2f(xq.z), bf2f(xq.w));
    const float4 at = *(const float4*)(att + c4);
    float4 acc = make_float4(0.f, 0.f, 0.f, 0.f);
    float den = 0.0f;

#define EDGE(vq) {                                                        \
        float4 vc = make_float4(bf2f(vq.x), bf2f(vq.y),                   \
                                bf2f(vq.z), bf2f(vq.w));                  \
        float f, p;                                                       \
        f = xn.x + vc.x; f = f > 0.f ? f : NEG_SLOPE * f; p  = f * at.x;  \
        f = xn.y + vc.y; f = f > 0.f ? f : NEG_SLOPE * f; p += f * at.y;  \
        f = xn.z + vc.z; f = f > 0.f ? f : NEG_SLOPE * f; p += f * at.z;  \
        f = xn.w + vc.w; f = f > 0.f ? f : NEG_SLOPE * f; p += f * at.w;  \
        p = rowsum16(p);                                                  \
        float ex = __expf(p);                                             \
        den += ex;                                                        \
        acc.x += ex * vc.x; acc.y += ex * vc.y;                           \
        acc.z += ex * vc.z; acc.w += ex * vc.w; }

    if (ne > 0) {
        // depth-2 pipeline; prefetch indices/rows run into the 16-int sentinel pad
        int sa = sp[0];
        int sb = sp[1];
        ushort4 va = *(const ushort4*)(xp + (size_t)sa * HC);
        ushort4 vb = *(const ushort4*)(xp + (size_t)sb * HC);
        sa = sp[2];
        sb = sp[3];
        int i = 0;
        for (; i + 1 < ne; i += 2) {
            ushort4 v0 = va, v1 = vb;
            va = *(const ushort4*)(xp + (size_t)sa * HC);
            vb = *(const ushort4*)(xp + (size_t)sb * HC);
            sa = sp[i + 4];
            sb = sp[i + 5];
            EDGE(v0);
            EDGE(v1);
        }
        if (i < ne) EDGE(va);
    }
#undef EDGE

    float r = 1.0f / (den > 0.0f ? den : 1.0f);
    const float4 b4 = *(const float4*)(bias + c4);
    float4 o;
    o.x = fmaxf(acc.x * r + b4.x, 0.0f);
    o.y = fmaxf(acc.y * r + b4.y, 0.0f);
    o.z = fmaxf(acc.z * r + b4.z, 0.0f);
    o.w = fmaxf(acc.w * r + b4.w, 0.0f);
    *(float4*)(out + (size_t)n * HC + c4) = o;
}

extern "C" void kernel_launch(void* const* d_in, const int* in_sizes, int n_in,
                              void* d_out, int out_size, void* d_ws, size_t ws_size,
                              hipStream_t stream) {
    const float* x    = (const float*)d_in[0];
    const int*   edge = (const int*)d_in[1];     // [2, E] int32
    const float* W    = (const float*)d_in[2];
    const float* att  = (const float*)d_in[3];
    const float* bias = (const float*)d_in[4];
    float* out = (float*)d_out;

    const int* src = edge;
    const int* dst = edge + N_EDGES;

    // workspace layout (16B-aligned)
    char* ws = (char*)d_ws;
    unsigned short* xlh = (unsigned short*)ws;          // 25,600,000 B (bf16 xl)
    int* cnt     = (int*)(ws + 25600000);               //   200,000 B
    int* done    = (int*)(ws + 25800000);               //        64 B (memset w/ cnt)
    int* rowL    = (int*)(ws + 25800064);               //   200,000 B
    int* ssorted = (int*)(ws + 26000064);               // 3,200,064 B (+16 pad ints)
    int* tops    = (int*)(ws + 29200192);               //     1,024 B
    int* topsS   = (int*)(ws + 29201216);               //     1,024 B
    // total ~29.2 MB

    hipMemsetAsync(cnt, 0, 200064, stream);  // cnt + done
    k_gemm_hist<<<GEMM_BLOCKS + HIST_BLOCKS, 256, 0, stream>>>(x, W, xlh, dst, cnt);
    k_scan<<<N_CHUNKS, 256, 0, stream>>>(cnt, rowL, tops, topsS, done);
    k_fill<<<(N_EDGES + 16 + 255) / 256, 256, 0, stream>>>(src, dst, cnt, rowL, topsS, ssorted);
    k_node<<<N_NODES / 4, 256, 0, stream>>>(xlh, rowL, topsS, ssorted, att, bias, out);
}